// Round 4
// baseline (513.181 us; speedup 1.0000x reference)
//
#include <hip/hip_runtime.h>
#include <stdint.h>

typedef __attribute__((ext_vector_type(16))) float f32x16;
typedef __attribute__((ext_vector_type(8))) short s16x8;

__device__ inline short bf16b(float f) {
  uint32_t x = __float_as_uint(f);
  return (short)((x + 0x7fffu + ((x >> 16) & 1u)) >> 16);  // RNE, finite inputs
}
__device__ inline float bfu(uint16_t u) { return __uint_as_float(((uint32_t)u) << 16); }

__device__ inline void gll16(const void* g, void* l) {
  __builtin_amdgcn_global_load_lds((const __attribute__((address_space(1))) void*)g,
                                   (__attribute__((address_space(3))) void*)l, 16, 0, 0);
}

// ---------------- weight pack: (co,ci,3,3) f32 -> 32x32x16 B-fragment order ----------------
// frag idx = ((tap*4 + chunk)*2 + ks)*4 + nblk ; lane l elem j:
//   co = nblk*32 + (l&31), ci = chunk*32 + ks*16 + (l>>5)*8 + j
__global__ __launch_bounds__(256) void packw_k(
    const float* w0, const float* w1, const float* w2, const float* w3,
    const float* w4, const float* w5, const float* w6, s16x8* dst) {
  const float* srcs[7] = {w0, w1, w2, w3, w4, w5, w6};
  const int widx = blockIdx.y;
  const float* src = srcs[widx];
  const int gid = blockIdx.x * 256 + threadIdx.x;  // [0,18432)
  const int lane = gid & 63, frag = gid >> 6;      // frag < 288
  const int nblk = frag & 3, ks = (frag >> 2) & 1, chunk = (frag >> 3) & 3, tap = frag >> 5;
  const int co = nblk * 32 + (lane & 31);
  const int cib = chunk * 32 + ks * 16 + (lane >> 5) * 8;
  s16x8 v;
#pragma unroll
  for (int j = 0; j < 8; ++j)
    v[j] = bf16b(src[((size_t)co * 128 + cib + j) * 9 + tap]);
  dst[(size_t)widx * 18432 + (size_t)frag * 64 + lane] = v;
}

// ---------------- NCHW f32 -> NHWC bf16 ----------------
template <int TW>
__global__ __launch_bounds__(256) void nchw2nhwc_k(
    const float* __restrict__ in, uint16_t* __restrict__ out, int H, int W) {
  __shared__ float tile[128][TW + 1];
  const int b = blockIdx.z, h = blockIdx.y, w0 = blockIdx.x * TW;
  for (int idx = threadIdx.x; idx < 128 * TW; idx += 256) {
    int c = idx / TW, w = idx - c * TW;
    tile[c][w] = in[(((size_t)b * 128 + c) * H + h) * W + w0 + w];
  }
  __syncthreads();
  for (int idx = threadIdx.x; idx < TW * 16; idx += 256) {
    int w = idx >> 4, cg = idx & 15;
    s16x8 v;
#pragma unroll
    for (int j = 0; j < 8; ++j) v[j] = bf16b(tile[cg * 8 + j][w]);
    *reinterpret_cast<s16x8*>(out + ((((size_t)b * H + h) * W + w0 + w) << 7) + cg * 8) = v;
  }
}

// ---------------- MFMA conv: 3x3, Cin=Cout=128, SAME pad, NHWC bf16 input ----------------
// Tile: 8 rows x 32 cols x 128 co. 4 waves: wm(2) x wn(2); wave = 128 px x 64 co,
// 32x32x16 MFMA, acc 4x2 f32x16. Input via global_load_lds, k-major LDS
// [kq(4)][row(10)][col(34)] 16B slots, double-buffered, one barrier per 32-ci chunk.
// Weights streamed from L2 with DEPTH-4 register ring (256-cyc MFMA cover >= L2 lat).
// Chunk loop fully unrolled -> ring slot (g&3) and weight offsets all compile-time.
// OMODE: 0 = NHWC, 1 = (b,w,h,e) gather, 3 = NCHW
template <int OMODE, bool RELU, typename Tout>
__global__ __launch_bounds__(256, 2) void convmf2_k(
    const uint16_t* __restrict__ in, const s16x8* __restrict__ wpk,
    const float* __restrict__ bias, Tout* __restrict__ out,
    const uint16_t* __restrict__ zp, int H, int W) {
  constexpr int CP = 34, RPCP = 10 * 34;  // 340
  constexpr int SLOTS = 4 * RPCP;         // 1360
  constexpr int SPT = 6;                  // 6*256 = 1536 padded slots
  __shared__ s16x8 lds[2][SPT * 256];
  const int b = blockIdx.z, r0 = blockIdx.y * 8, c0 = blockIdx.x * 32;
  const int tid = threadIdx.x, lane = tid & 63;
  const int wv = tid >> 6, wm = wv >> 1, wn = wv & 1;
  const int wbase = tid & 192;

  // per-slot global source addresses (once)
  const uint16_t* gsrc[SPT];
#pragma unroll
  for (int i = 0; i < SPT; ++i) {
    const int s = tid + i * 256;
    const int kq = s / RPCP;
    const int rem = s - kq * RPCP;
    const int r = rem / CP, c = rem - r * CP;
    const int gr = r0 + r - 1, gc = c0 + c - 1;
    const bool ok = (s < SLOTS) && gr >= 0 && gr < H && gc >= 0 && gc < W;
    gsrc[i] = ok ? (in + (((size_t)b * H + gr) * W + gc) * 128 + kq * 8) : zp;
  }

  // prologue: stage chunk 0 into buf 0
#pragma unroll
  for (int i = 0; i < SPT; ++i) gll16(gsrc[i], &lds[0][wbase + i * 256]);

  f32x16 acc[4][2];
#pragma unroll
  for (int i = 0; i < 4; ++i)
#pragma unroll
    for (int j = 0; j < 2; ++j)
#pragma unroll
      for (int r = 0; r < 16; ++r) acc[i][j][r] = 0.f;

  // weight ring: depth 4 (t9 steps), 2 n-frags each
  const s16x8* __restrict__ wb = wpk + wn * 128 + lane;  // + step_off + nf*64
  s16x8 bw[4][2];
#pragma unroll
  for (int g = 0; g < 4; ++g) {  // chunk 0, t9 = g
    const int tap = g >> 1, ks = g & 1;
    const int off = ((tap * 4 + 0) * 2 + ks) * 256;
    bw[g][0] = wb[off];
    bw[g][1] = wb[off + 64];
  }

  const int rowb = wm * 4 * CP + (lane >> 5) * RPCP + (lane & 31);
  __syncthreads();

#pragma unroll
  for (int chunk = 0; chunk < 4; ++chunk) {
    const int cb = chunk & 1;
    if (chunk < 3) {  // issue next chunk's DMA; completes under this chunk's MFMA
#pragma unroll
      for (int i = 0; i < SPT; ++i)
        gll16(gsrc[i] + (chunk + 1) * 32, &lds[cb ^ 1][wbase + i * 256]);
    }
    const s16x8* __restrict__ Lb = &lds[cb][rowb];
#pragma unroll
    for (int t9 = 0; t9 < 18; ++t9) {  // t9 = tap*2 + ks
      const int g = chunk * 18 + t9;
      const int slot = g & 3;  // compile-time (both loops unrolled)
      const int tap = t9 >> 1, ks = t9 & 1;
      const int ky = tap / 3, kx = tap - ky * 3;
      const s16x8 cw0 = bw[slot][0], cw1 = bw[slot][1];
#pragma unroll
      for (int mf = 0; mf < 4; ++mf) {
        const s16x8 av = Lb[ks * (2 * RPCP) + (mf + ky) * CP + kx];
        acc[mf][0] = __builtin_amdgcn_mfma_f32_32x32x16_bf16(av, cw0, acc[mf][0], 0, 0, 0);
        acc[mf][1] = __builtin_amdgcn_mfma_f32_32x32x16_bf16(av, cw1, acc[mf][1], 0, 0, 0);
      }
      if (g + 4 < 72) {  // refill slot with step g+4 (may cross chunk boundary)
        const int gn = g + 4;
        const int cn = gn / 18, tn = gn - cn * 18;
        const int tapn = tn >> 1, ksn = tn & 1;
        const int off = ((tapn * 4 + cn) * 2 + ksn) * 256;
        bw[slot][0] = wb[off];
        bw[slot][1] = wb[off + 64];
      }
    }
    if (chunk < 3) __syncthreads();
  }

  // epilogue: C/D map col(co)=lane&31, image-col = (reg&3)+8*(reg>>2)+4*(lane>>5)
#pragma unroll
  for (int nf = 0; nf < 2; ++nf) {
    const int co = wn * 64 + nf * 32 + (lane & 31);
    const float bv = bias[co];
#pragma unroll
    for (int mf = 0; mf < 4; ++mf) {
      const int gr = r0 + wm * 4 + mf;
#pragma unroll
      for (int reg = 0; reg < 16; ++reg) {
        const int gc = c0 + (reg & 3) + 8 * (reg >> 2) + 4 * (lane >> 5);
        float v = acc[mf][nf][reg] + bv;
        if (RELU) v = fmaxf(v, 0.f);
        size_t idx;
        if (OMODE == 0)      idx = (((size_t)b * H + gr) * W + gc) * 128 + co;
        else if (OMODE == 1) idx = (((size_t)b * W + gc) * H + gr) * 128 + co;
        else                 idx = (((size_t)b * 128 + co) * H + gr) * W + gc;
        if constexpr (sizeof(Tout) == 2) ((uint16_t*)out)[idx] = (uint16_t)bf16b(v);
        else out[idx] = v;
      }
    }
  }
}

// ---------------- attention: dot + softmax ----------------
__global__ __launch_bounds__(128) void attn_dot_k(
    const float* __restrict__ qg, const uint16_t* __restrict__ Kg,
    const int* __restrict__ u, float* __restrict__ pout) {
  const int bs = blockIdx.x;
  const int b = bs >> 10;
  const int tid = threadIdx.x;  // h
  __shared__ float sq[128], sd[128];
  sq[tid] = qg[(size_t)bs * 128 + tid];
  int w = u[bs]; w = w < 0 ? 0 : (w > 511 ? 511 : w);
  __syncthreads();
  const uint32_t* kp = reinterpret_cast<const uint32_t*>(
      Kg + (((size_t)b * 512 + w) * 128 + tid) * 128);
  float acc = 0.f;
#pragma unroll 8
  for (int i = 0; i < 64; ++i) {
    uint32_t v = kp[i];
    acc = fmaf(sq[2 * i],     __uint_as_float(v << 16), acc);
    acc = fmaf(sq[2 * i + 1], __uint_as_float(v & 0xffff0000u), acc);
  }
  sd[tid] = acc * 0.17677669529663687f;
  __syncthreads();
  float mx = -1e30f;
  for (int i = 0; i < 128; ++i) mx = fmaxf(mx, sd[i]);
  float e = expf(sd[tid] - mx);
  __syncthreads();
  sd[tid] = e;
  __syncthreads();
  float sum = 0.f;
  for (int i = 0; i < 128; ++i) sum += sd[i];
  pout[(size_t)bs * 128 + tid] = e / sum;
}

// ---------------- attention: P @ V_gathered -> (b,s,e) bf16 ----------------
__global__ __launch_bounds__(128) void attn_pv_k(
    const float* __restrict__ pin, const uint16_t* __restrict__ Vg,
    const int* __restrict__ u, uint16_t* __restrict__ aout) {
  const int bs = blockIdx.x;
  const int b = bs >> 10;
  const int tid = threadIdx.x;  // e
  __shared__ float sp[128];
  sp[tid] = pin[(size_t)bs * 128 + tid];
  int w = u[bs]; w = w < 0 ? 0 : (w > 511 ? 511 : w);
  __syncthreads();
  const uint16_t* vp = Vg + ((size_t)b * 512 + w) * 16384 + tid;
  float acc = 0.f;
#pragma unroll 8
  for (int h = 0; h < 128; ++h)
    acc = fmaf(sp[h], bfu(vp[h * 128]), acc);
  aout[(size_t)bs * 128 + tid] = (uint16_t)bf16b(acc);
}

// ---------------- launch ----------------
extern "C" void kernel_launch(void* const* d_in, const int* in_sizes, int n_in,
                              void* d_out, int out_size, void* d_ws, size_t ws_size,
                              hipStream_t stream) {
  const float* x      = (const float*)d_in[0];
  const float* y      = (const float*)d_in[1];
  const int*   u      = (const int*)d_in[2];
  const float* q_w1   = (const float*)d_in[3];
  const float* q_b1   = (const float*)d_in[4];
  const float* q_w2   = (const float*)d_in[5];
  const float* q_b2   = (const float*)d_in[6];
  const float* k_w1   = (const float*)d_in[7];
  const float* k_b1   = (const float*)d_in[8];
  const float* k_w2   = (const float*)d_in[9];
  const float* k_b2   = (const float*)d_in[10];
  const float* v_w1   = (const float*)d_in[11];
  const float* v_b1   = (const float*)d_in[12];
  const float* v_w2   = (const float*)d_in[13];
  const float* v_b2   = (const float*)d_in[14];
  const float* proj_w = (const float*)d_in[15];
  const float* proj_b = (const float*)d_in[16];
  float* out = (float*)d_out;

  char* ws = (char*)d_ws;
  const size_t MB = 1 << 20;
  const size_t BIG = 64 * MB;
  const bool tierB = ws_size >= 203 * MB;  // 3 big buffers -> skip 2nd y-transform
  uint16_t* A  = (uint16_t*)ws;            // ybf (NHWC bf16)
  uint16_t* Bb = (uint16_t*)(ws + BIG);    // k1 / v1
  uint16_t* KV = tierB ? (uint16_t*)(ws + 2 * BIG) : A;  // K / V in (b,w,h,e)
  char* sm = ws + (tierB ? 3 : 2) * BIG;
  float*    qg  = (float*)sm;                    // 2 MB
  float*    pb  = (float*)(sm + 2 * MB);         // 2 MB
  uint16_t* xbf = (uint16_t*)(sm + 4 * MB);      // 1 MB
  uint16_t* t1  = (uint16_t*)(sm + 5 * MB);      // 1 MB
  uint16_t* ab  = (uint16_t*)(sm + 6 * MB);      // 1 MB
  s16x8*    wpk = (s16x8*)(sm + 7 * MB);         // ~2.02 MB
  uint16_t* zp  = (uint16_t*)(sm + 10 * MB);     // 1 KB zeros

  hipMemsetAsync(zp, 0, 1024, stream);
  packw_k<<<dim3(72, 7), 256, 0, stream>>>(q_w1, q_w2, k_w1, k_w2, v_w1, v_w2, proj_w, wpk);
  nchw2nhwc_k<32><<<dim3(1, 32, 4), 256, 0, stream>>>(x, xbf, 32, 32);
  nchw2nhwc_k<64><<<dim3(8, 128, 4), 256, 0, stream>>>(y, A, 128, 512);
  // Q path
  convmf2_k<0, true,  uint16_t><<<dim3(1, 4, 4), 256, 0, stream>>>(xbf, wpk + 0 * 18432, q_b1, t1, zp, 32, 32);
  convmf2_k<0, false, float   ><<<dim3(1, 4, 4), 256, 0, stream>>>(t1,  wpk + 1 * 18432, q_b2, qg, zp, 32, 32);
  // K path
  convmf2_k<0, true,  uint16_t><<<dim3(16, 16, 4), 256, 0, stream>>>(A,  wpk + 2 * 18432, k_b1, Bb, zp, 128, 512);
  convmf2_k<1, false, uint16_t><<<dim3(16, 16, 4), 256, 0, stream>>>(Bb, wpk + 3 * 18432, k_b2, KV, zp, 128, 512);
  attn_dot_k<<<dim3(4096), 128, 0, stream>>>(qg, KV, u, pb);
  // V path
  if (!tierB) nchw2nhwc_k<64><<<dim3(8, 128, 4), 256, 0, stream>>>(y, A, 128, 512);
  convmf2_k<0, true,  uint16_t><<<dim3(16, 16, 4), 256, 0, stream>>>(A,  wpk + 4 * 18432, v_b1, Bb, zp, 128, 512);
  convmf2_k<1, false, uint16_t><<<dim3(16, 16, 4), 256, 0, stream>>>(Bb, wpk + 5 * 18432, v_b2, KV, zp, 128, 512);
  attn_pv_k<<<dim3(4096), 128, 0, stream>>>(pb, KV, u, ab);
  // proj
  convmf2_k<3, true, float><<<dim3(1, 4, 4), 256, 0, stream>>>(ab, wpk + 6 * 18432, proj_b, out, zp, 32, 32);
}

// Round 5
// 429.977 us; speedup vs baseline: 1.1935x; 1.1935x over previous
//
#include <hip/hip_runtime.h>
#include <stdint.h>

typedef __attribute__((ext_vector_type(16))) float f32x16;
typedef __attribute__((ext_vector_type(8))) short s16x8;

__device__ inline short bf16b(float f) {
  uint32_t x = __float_as_uint(f);
  return (short)((x + 0x7fffu + ((x >> 16) & 1u)) >> 16);  // RNE, finite inputs
}
__device__ inline float bfu(uint16_t u) { return __uint_as_float(((uint32_t)u) << 16); }

__device__ inline void gll16(const void* g, void* l) {
  __builtin_amdgcn_global_load_lds((const __attribute__((address_space(1))) void*)g,
                                   (__attribute__((address_space(3))) void*)l, 16, 0, 0);
}

// ---------------- weight pack: (co,ci,3,3) f32 -> 32x32x16 B-fragment order ----------------
// frag idx = ((tap*4 + chunk)*2 + ks)*4 + nblk ; lane l elem j:
//   co = nblk*32 + (l&31), ci = chunk*32 + ks*16 + (l>>5)*8 + j
__global__ __launch_bounds__(256) void packw_k(
    const float* w0, const float* w1, const float* w2, const float* w3,
    const float* w4, const float* w5, const float* w6, s16x8* dst) {
  const float* srcs[7] = {w0, w1, w2, w3, w4, w5, w6};
  const int widx = blockIdx.y;
  const float* src = srcs[widx];
  const int gid = blockIdx.x * 256 + threadIdx.x;  // [0,18432)
  const int lane = gid & 63, frag = gid >> 6;      // frag < 288
  const int nblk = frag & 3, ks = (frag >> 2) & 1, chunk = (frag >> 3) & 3, tap = frag >> 5;
  const int co = nblk * 32 + (lane & 31);
  const int cib = chunk * 32 + ks * 16 + (lane >> 5) * 8;
  s16x8 v;
#pragma unroll
  for (int j = 0; j < 8; ++j)
    v[j] = bf16b(src[((size_t)co * 128 + cib + j) * 9 + tap]);
  dst[(size_t)widx * 18432 + (size_t)frag * 64 + lane] = v;
}

// ---------------- NCHW f32 -> NHWC bf16 ----------------
template <int TW>
__global__ __launch_bounds__(256) void nchw2nhwc_k(
    const float* __restrict__ in, uint16_t* __restrict__ out, int H, int W) {
  __shared__ float tile[128][TW + 1];
  const int b = blockIdx.z, h = blockIdx.y, w0 = blockIdx.x * TW;
  for (int idx = threadIdx.x; idx < 128 * TW; idx += 256) {
    int c = idx / TW, w = idx - c * TW;
    tile[c][w] = in[(((size_t)b * 128 + c) * H + h) * W + w0 + w];
  }
  __syncthreads();
  for (int idx = threadIdx.x; idx < TW * 16; idx += 256) {
    int w = idx >> 4, cg = idx & 15;
    s16x8 v;
#pragma unroll
    for (int j = 0; j < 8; ++j) v[j] = bf16b(tile[cg * 8 + j][w]);
    *reinterpret_cast<s16x8*>(out + ((((size_t)b * H + h) * W + w0 + w) << 7) + cg * 8) = v;
  }
}

// ---------------- MFMA conv v3: 3x3, Cin=Cout=128, SAME pad, NHWC bf16 input ----------------
// Tile: 4 rows x 32 cols x 128 co. 4 waves, each = same 128 px x 32 co (wn = wave id).
// Per-chunk weights (18 frags x 16B = 72 VGPR) live ENTIRELY in registers, refilled for
// chunk c+1 right after last use in chunk c -> zero exposed vmcnt waits in the loop.
// A staged via global_load_lds, k-major LDS [kq(4)][row(6)][col(34)], double-buffered.
// Inner: 6 (ks,kx) sub-blocks; 6 deduped ds_read_b128 (ar dbuf, 1 sub-block ahead)
// feed 12 MFMA (ky x mf) wrapped in s_setprio.  OMODE: 0=NHWC, 1=(b,w,h,e), 3=NCHW
template <int OMODE, bool RELU, typename Tout>
__global__ __launch_bounds__(256, 2) void convmf3_k(
    const uint16_t* __restrict__ in, const s16x8* __restrict__ wpk,
    const float* __restrict__ bias, Tout* __restrict__ out,
    const uint16_t* __restrict__ zp, int H, int W) {
  constexpr int CP = 34, RP = 6, RPCP = RP * CP;  // 204
  constexpr int SLOTS = 4 * RPCP;                 // 816
  constexpr int SPT = 4;                          // 1024 padded slots
  __shared__ s16x8 lds[2][SPT * 256];
  const int b = blockIdx.z, r0 = blockIdx.y * 4, c0 = blockIdx.x * 32;
  const int tid = threadIdx.x, lane = tid & 63, wn = tid >> 6;
  const int wbase = tid & 192;

  // per-slot global source addresses (once)
  const uint16_t* gsrc[SPT];
#pragma unroll
  for (int i = 0; i < SPT; ++i) {
    const int s = tid + i * 256;
    const int kq = s / RPCP;
    const int rem = s - kq * RPCP;
    const int r = rem / CP, c = rem - r * CP;
    const int gr = r0 + r - 1, gc = c0 + c - 1;
    const bool ok = (s < SLOTS) && gr >= 0 && gr < H && gc >= 0 && gc < W;
    gsrc[i] = ok ? (in + (((size_t)b * H + gr) * W + gc) * 128 + kq * 8) : zp;
  }

  // weight base for this wave's co-block; frag off = ((tap*4+chunk)*2+ks)*256
  const s16x8* __restrict__ wbl = wpk + wn * 64 + lane;
  s16x8 wf[18];
#pragma unroll
  for (int t9 = 0; t9 < 18; ++t9) {  // chunk 0 preload
    const int tap = t9 >> 1, ks = t9 & 1;
    wf[t9] = wbl[(tap * 8 + ks) * 256];
  }

  // prologue: stage chunk 0 into buf 0
#pragma unroll
  for (int i = 0; i < SPT; ++i) gll16(gsrc[i], &lds[0][wbase + i * 256]);

  f32x16 acc[4];
#pragma unroll
  for (int i = 0; i < 4; ++i)
#pragma unroll
    for (int r = 0; r < 16; ++r) acc[i][r] = 0.f;

  const int abase = (lane >> 5) * RPCP + (lane & 31);
  __syncthreads();

#pragma unroll
  for (int chunk = 0; chunk < 4; ++chunk) {
    const int cb = chunk & 1;
    if (chunk < 3) {  // next chunk's DMA; completes under this chunk's MFMA
#pragma unroll
      for (int i = 0; i < SPT; ++i)
        gll16(gsrc[i] + (chunk + 1) * 32, &lds[cb ^ 1][wbase + i * 256]);
    }
    const s16x8* __restrict__ Lb = &lds[cb][abase];
    s16x8 arA[6], arB[6];
#pragma unroll
    for (int r = 0; r < 6; ++r) arA[r] = Lb[r * CP];  // sub-block 0 (ks=0,kx=0)
#pragma unroll
    for (int j = 0; j < 6; ++j) {  // j = ks*3 + kx
      const int ks = j / 3, kx = j - ks * 3;
      if (j < 5) {  // prefetch next sub-block's 6 unique rows
        const int jn = j + 1, ksn = jn / 3, kxn = jn - ksn * 3;
#pragma unroll
        for (int r = 0; r < 6; ++r) {
          s16x8 v = Lb[ksn * 2 * RPCP + r * CP + kxn];
          if (j & 1) arA[r] = v; else arB[r] = v;
        }
      }
      __builtin_amdgcn_s_setprio(1);
#pragma unroll
      for (int ky = 0; ky < 3; ++ky) {
        const int t9 = (ky * 3 + kx) * 2 + ks;
#pragma unroll
        for (int mf = 0; mf < 4; ++mf) {
          const s16x8 a = (j & 1) ? arB[mf + ky] : arA[mf + ky];
          acc[mf] = __builtin_amdgcn_mfma_f32_32x32x16_bf16(a, wf[t9], acc[mf], 0, 0, 0);
        }
      }
      __builtin_amdgcn_s_setprio(0);
      if (chunk < 3) {  // refill this sub-block's 3 weight frags for chunk+1
#pragma unroll
        for (int ky = 0; ky < 3; ++ky) {
          const int tap = ky * 3 + kx;
          wf[tap * 2 + ks] = wbl[((tap * 4 + chunk + 1) * 2 + ks) * 256];
        }
      }
    }
    if (chunk < 3) __syncthreads();
  }

  // epilogue: C/D map co=lane&31, px = (reg&3)+8*(reg>>2)+4*(lane>>5)
  const int co = wn * 32 + (lane & 31);
  const float bv = bias[co];
#pragma unroll
  for (int mf = 0; mf < 4; ++mf) {
    const int gr = r0 + mf;
#pragma unroll
    for (int reg = 0; reg < 16; ++reg) {
      const int gc = c0 + (reg & 3) + 8 * (reg >> 2) + 4 * (lane >> 5);
      float v = acc[mf][reg] + bv;
      if (RELU) v = fmaxf(v, 0.f);
      size_t idx;
      if (OMODE == 0)      idx = (((size_t)b * H + gr) * W + gc) * 128 + co;
      else if (OMODE == 1) idx = (((size_t)b * W + gc) * H + gr) * 128 + co;
      else                 idx = (((size_t)b * 128 + co) * H + gr) * W + gc;
      if constexpr (sizeof(Tout) == 2) ((uint16_t*)out)[idx] = (uint16_t)bf16b(v);
      else out[idx] = v;
    }
  }
}

// ---------------- attention: dot + softmax ----------------
__global__ __launch_bounds__(128) void attn_dot_k(
    const float* __restrict__ qg, const uint16_t* __restrict__ Kg,
    const int* __restrict__ u, float* __restrict__ pout) {
  const int bs = blockIdx.x;
  const int b = bs >> 10;
  const int tid = threadIdx.x;  // h
  __shared__ float sq[128], sd[128];
  sq[tid] = qg[(size_t)bs * 128 + tid];
  int w = u[bs]; w = w < 0 ? 0 : (w > 511 ? 511 : w);
  __syncthreads();
  const uint32_t* kp = reinterpret_cast<const uint32_t*>(
      Kg + (((size_t)b * 512 + w) * 128 + tid) * 128);
  float acc = 0.f;
#pragma unroll 8
  for (int i = 0; i < 64; ++i) {
    uint32_t v = kp[i];
    acc = fmaf(sq[2 * i],     __uint_as_float(v << 16), acc);
    acc = fmaf(sq[2 * i + 1], __uint_as_float(v & 0xffff0000u), acc);
  }
  sd[tid] = acc * 0.17677669529663687f;
  __syncthreads();
  float mx = -1e30f;
  for (int i = 0; i < 128; ++i) mx = fmaxf(mx, sd[i]);
  float e = expf(sd[tid] - mx);
  __syncthreads();
  sd[tid] = e;
  __syncthreads();
  float sum = 0.f;
  for (int i = 0; i < 128; ++i) sum += sd[i];
  pout[(size_t)bs * 128 + tid] = e / sum;
}

// ---------------- attention: P @ V_gathered -> (b,s,e) bf16 ----------------
__global__ __launch_bounds__(128) void attn_pv_k(
    const float* __restrict__ pin, const uint16_t* __restrict__ Vg,
    const int* __restrict__ u, uint16_t* __restrict__ aout) {
  const int bs = blockIdx.x;
  const int b = bs >> 10;
  const int tid = threadIdx.x;  // e
  __shared__ float sp[128];
  sp[tid] = pin[(size_t)bs * 128 + tid];
  int w = u[bs]; w = w < 0 ? 0 : (w > 511 ? 511 : w);
  __syncthreads();
  const uint16_t* vp = Vg + ((size_t)b * 512 + w) * 16384 + tid;
  float acc = 0.f;
#pragma unroll 8
  for (int h = 0; h < 128; ++h)
    acc = fmaf(sp[h], bfu(vp[h * 128]), acc);
  aout[(size_t)bs * 128 + tid] = (uint16_t)bf16b(acc);
}

// ---------------- launch ----------------
extern "C" void kernel_launch(void* const* d_in, const int* in_sizes, int n_in,
                              void* d_out, int out_size, void* d_ws, size_t ws_size,
                              hipStream_t stream) {
  const float* x      = (const float*)d_in[0];
  const float* y      = (const float*)d_in[1];
  const int*   u      = (const int*)d_in[2];
  const float* q_w1   = (const float*)d_in[3];
  const float* q_b1   = (const float*)d_in[4];
  const float* q_w2   = (const float*)d_in[5];
  const float* q_b2   = (const float*)d_in[6];
  const float* k_w1   = (const float*)d_in[7];
  const float* k_b1   = (const float*)d_in[8];
  const float* k_w2   = (const float*)d_in[9];
  const float* k_b2   = (const float*)d_in[10];
  const float* v_w1   = (const float*)d_in[11];
  const float* v_b1   = (const float*)d_in[12];
  const float* v_w2   = (const float*)d_in[13];
  const float* v_b2   = (const float*)d_in[14];
  const float* proj_w = (const float*)d_in[15];
  const float* proj_b = (const float*)d_in[16];
  float* out = (float*)d_out;

  char* ws = (char*)d_ws;
  const size_t MB = 1 << 20;
  const size_t BIG = 64 * MB;
  const bool tierB = ws_size >= 203 * MB;  // 3 big buffers -> skip 2nd y-transform
  uint16_t* A  = (uint16_t*)ws;            // ybf (NHWC bf16)
  uint16_t* Bb = (uint16_t*)(ws + BIG);    // k1 / v1
  uint16_t* KV = tierB ? (uint16_t*)(ws + 2 * BIG) : A;  // K / V in (b,w,h,e)
  char* sm = ws + (tierB ? 3 : 2) * BIG;
  float*    qg  = (float*)sm;                    // 2 MB
  float*    pb  = (float*)(sm + 2 * MB);         // 2 MB
  uint16_t* xbf = (uint16_t*)(sm + 4 * MB);      // 1 MB
  uint16_t* t1  = (uint16_t*)(sm + 5 * MB);      // 1 MB
  uint16_t* ab  = (uint16_t*)(sm + 6 * MB);      // 1 MB
  s16x8*    wpk = (s16x8*)(sm + 7 * MB);         // ~2.02 MB
  uint16_t* zp  = (uint16_t*)(sm + 10 * MB);     // 1 KB zeros

  hipMemsetAsync(zp, 0, 1024, stream);
  packw_k<<<dim3(72, 7), 256, 0, stream>>>(q_w1, q_w2, k_w1, k_w2, v_w1, v_w2, proj_w, wpk);
  nchw2nhwc_k<32><<<dim3(1, 32, 4), 256, 0, stream>>>(x, xbf, 32, 32);
  nchw2nhwc_k<64><<<dim3(8, 128, 4), 256, 0, stream>>>(y, A, 128, 512);
  // Q path
  convmf3_k<0, true,  uint16_t><<<dim3(1, 8, 4), 256, 0, stream>>>(xbf, wpk + 0 * 18432, q_b1, t1, zp, 32, 32);
  convmf3_k<0, false, float   ><<<dim3(1, 8, 4), 256, 0, stream>>>(t1,  wpk + 1 * 18432, q_b2, qg, zp, 32, 32);
  // K path
  convmf3_k<0, true,  uint16_t><<<dim3(16, 32, 4), 256, 0, stream>>>(A,  wpk + 2 * 18432, k_b1, Bb, zp, 128, 512);
  convmf3_k<1, false, uint16_t><<<dim3(16, 32, 4), 256, 0, stream>>>(Bb, wpk + 3 * 18432, k_b2, KV, zp, 128, 512);
  attn_dot_k<<<dim3(4096), 128, 0, stream>>>(qg, KV, u, pb);
  // V path
  if (!tierB) nchw2nhwc_k<64><<<dim3(8, 128, 4), 256, 0, stream>>>(y, A, 128, 512);
  convmf3_k<0, true,  uint16_t><<<dim3(16, 32, 4), 256, 0, stream>>>(A,  wpk + 4 * 18432, v_b1, Bb, zp, 128, 512);
  convmf3_k<1, false, uint16_t><<<dim3(16, 32, 4), 256, 0, stream>>>(Bb, wpk + 5 * 18432, v_b2, KV, zp, 128, 512);
  attn_pv_k<<<dim3(4096), 128, 0, stream>>>(pb, KV, u, ab);
  // proj
  convmf3_k<3, true, float><<<dim3(1, 8, 4), 256, 0, stream>>>(ab, wpk + 6 * 18432, proj_b, out, zp, 32, 32);
}